// Round 3
// baseline (126.462 us; speedup 1.0000x reference)
//
#include <hip/hip_runtime.h>
#include <hip/hip_bf16.h>

// out[b,p] = sum_{e,f} x[b,i_p,e] * K[f,p,e] * x[b,j_p,f]
//
// MFMA formulation, per pair p:
//   Y = Xj @ K_p          (2048x64 @ 64x64, bf16 split-3 MFMA, fp32 accum)
//   out[:,p] = rowsum(Y * Xi)   (fp32 VALU epilogue)
//
// Split-bf16: v = hi + lo (both bf16); acc += Ah*Bh + Ah*Bl + Al*Bh -> rel err ~1e-5.
//
// Prepass 1: x (fp32) -> x_hi, x_lo (bf16, same [B][F][E] layout)
// Prepass 2: kern (fp32) -> B-fragment-packed hi/lo so the main kernel's
//            B loads are a single coalesced 16B/lane read.
// Fallback:  if ws_size is too small for the staging buffers, run the
//            pure-fp32 VALU kernel (correct, ~70us).

constexpr int BATCH  = 2048;
constexpr int FIELDS = 32;
constexpr int EMBED  = 64;
constexpr int PAIRS  = FIELDS * (FIELDS - 1) / 2;  // 496

typedef __attribute__((ext_vector_type(8))) short  short8;   // 8 bf16 = 4 VGPR
typedef __attribute__((ext_vector_type(4))) float  f32x4;

constexpr size_t XN      = (size_t)BATCH * FIELDS * EMBED;   // 4,194,304 elems
constexpr size_t KPN     = (size_t)PAIRS * 2 * 4 * 64 * 8;   // 2,031,616 elems
constexpr size_t XH_OFF  = 0;
constexpr size_t XL_OFF  = XH_OFF + XN * 2;
constexpr size_t KPH_OFF = XL_OFF + XN * 2;
constexpr size_t KPL_OFF = KPH_OFF + KPN * 2;
constexpr size_t WS_NEED = KPL_OFF + KPN * 2;                // ~24.9 MB

// ---- fp32 -> bf16 RNE split helpers (bit-level, no API dependence) ----
__device__ __forceinline__ unsigned short f32_to_bf16_rne(float f) {
    unsigned int u = __float_as_uint(f);
    u = u + 0x7fffu + ((u >> 16) & 1u);
    return (unsigned short)(u >> 16);
}
__device__ __forceinline__ float bf16_bits_to_f32(unsigned short h) {
    return __uint_as_float(((unsigned int)h) << 16);
}

// ---- Prepass 1: x -> x_hi, x_lo ----
__global__ __launch_bounds__(256) void convert_x_kernel(
    const float* __restrict__ x,
    unsigned short* __restrict__ xh,
    unsigned short* __restrict__ xl)
{
    const int idx = (int)blockIdx.x * 256 + (int)threadIdx.x;  // 4 floats per thread
    const float4 v = ((const float4*)x)[idx];
    const float vv[4] = {v.x, v.y, v.z, v.w};
    unsigned short h[4], l[4];
    #pragma unroll
    for (int j = 0; j < 4; ++j) {
        const unsigned short hb = f32_to_bf16_rne(vv[j]);
        h[j] = hb;
        l[j] = f32_to_bf16_rne(vv[j] - bf16_bits_to_f32(hb));
    }
    ((ushort4*)xh)[idx] = make_ushort4(h[0], h[1], h[2], h[3]);
    ((ushort4*)xl)[idx] = make_ushort4(l[0], l[1], l[2], l[3]);
}

// ---- Prepass 2: kern -> packed B-fragments (hi/lo) ----
// Packed layout: chunk index t = ((pair*2 + ks)*4 + nc)*64 + lane, 8 bf16 per chunk:
//   elem jj = K[f = ks*32 + (lane>>4)*8 + jj][pair][e = nc*16 + (lane&15)]
__global__ __launch_bounds__(256) void pack_k_kernel(
    const float* __restrict__ kern,
    unsigned short* __restrict__ kph,
    unsigned short* __restrict__ kpl)
{
    const int t    = (int)blockIdx.x * 256 + (int)threadIdx.x;  // < 253,952 = PAIRS*512
    const int lane = t & 63;
    const int nc   = (t >> 6) & 3;
    const int ks   = (t >> 8) & 1;
    const int pair = t >> 9;
    const int e    = nc * 16 + (lane & 15);
    const int f0   = ks * 32 + (lane >> 4) * 8;

    unsigned short h[8], l[8];
    #pragma unroll
    for (int jj = 0; jj < 8; ++jj) {
        const float v = kern[((size_t)(f0 + jj) * PAIRS + pair) * EMBED + e];
        const unsigned short hb = f32_to_bf16_rne(v);
        h[jj] = hb;
        l[jj] = f32_to_bf16_rne(v - bf16_bits_to_f32(hb));
    }
    #pragma unroll
    for (int jj = 0; jj < 8; ++jj) {
        kph[(size_t)t * 8 + jj] = h[jj];
        kpl[(size_t)t * 8 + jj] = l[jj];
    }
}

// ---- Main MFMA kernel ----
// grid = 496 pairs * 8 Mtiles; block = 256 (4 waves); wave tile = 64 batch x 64 e.
__global__ __launch_bounds__(256) void opn_mfma_kernel(
    const float* __restrict__ x,
    const unsigned short* __restrict__ xh,
    const unsigned short* __restrict__ xl,
    const unsigned short* __restrict__ kph,
    const unsigned short* __restrict__ kpl,
    float* __restrict__ out)
{
    const int bid  = (int)blockIdx.x;
    const int p    = bid >> 3;                 // pair (8 consecutive blocks share K_p)
    const int mt   = bid & 7;                  // M tile of 256 batches
    const int wave = (int)threadIdx.x >> 6;
    const int lane = (int)threadIdx.x & 63;
    const int Mb   = mt * 256 + wave * 64;     // this wave's first batch row
    const int g    = lane >> 4;                // k-group / row-group
    const int c    = lane & 15;                // row (A) / col (B,D) within fragment

    // pair -> (i, j) per jnp.triu_indices(FIELDS, k=1) row-major order
    int i = 0, rem = p;
    while (rem >= FIELDS - 1 - i) { rem -= FIELDS - 1 - i; ++i; }
    const int jf = i + 1 + rem;

    f32x4 acc[4][4];
    #pragma unroll
    for (int mr = 0; mr < 4; ++mr)
        #pragma unroll
        for (int nc = 0; nc < 4; ++nc)
            acc[mr][nc] = (f32x4){0.f, 0.f, 0.f, 0.f};

    #pragma unroll
    for (int ks = 0; ks < 2; ++ks) {
        // A fragments: A[m][k] = x_?[row = Mb+mr*16+c][field jf][k = ks*32+g*8 .. +7]
        short8 ah[4], al[4];
        #pragma unroll
        for (int mr = 0; mr < 4; ++mr) {
            const int row = Mb + mr * 16 + c;
            const size_t off = ((size_t)row * FIELDS + jf) * EMBED + ks * 32 + g * 8;
            ah[mr] = *(const short8*)(xh + off);
            al[mr] = *(const short8*)(xl + off);
        }
        // B fragments: packed, 16B per lane
        short8 bh[4], bl[4];
        #pragma unroll
        for (int nc = 0; nc < 4; ++nc) {
            const size_t kidx = (((size_t)(p * 2 + ks) * 4 + nc) * 64 + lane) * 8;
            bh[nc] = *(const short8*)(kph + kidx);
            bl[nc] = *(const short8*)(kpl + kidx);
        }
        #pragma unroll
        for (int mr = 0; mr < 4; ++mr) {
            #pragma unroll
            for (int nc = 0; nc < 4; ++nc) {
                acc[mr][nc] = __builtin_amdgcn_mfma_f32_16x16x32_bf16(ah[mr], bh[nc], acc[mr][nc], 0, 0, 0);
                acc[mr][nc] = __builtin_amdgcn_mfma_f32_16x16x32_bf16(ah[mr], bl[nc], acc[mr][nc], 0, 0, 0);
                acc[mr][nc] = __builtin_amdgcn_mfma_f32_16x16x32_bf16(al[mr], bh[nc], acc[mr][nc], 0, 0, 0);
            }
        }
    }

    // Epilogue: out[row, p] = sum_e D[row][e] * x[row][i][e]
    // D layout (m89): reg t of acc[mr][nc] = D[row = Mb+mr*16+4g+t][e = nc*16+c]
    float z[4][4];
    #pragma unroll
    for (int mr = 0; mr < 4; ++mr)
        #pragma unroll
        for (int t = 0; t < 4; ++t)
            z[mr][t] = 0.f;

    const size_t xi_base = (size_t)i * EMBED + c;
    #pragma unroll
    for (int mr = 0; mr < 4; ++mr) {
        #pragma unroll
        for (int t = 0; t < 4; ++t) {
            const int row = Mb + mr * 16 + 4 * g + t;
            const float* xi = x + (size_t)row * (FIELDS * EMBED) + xi_base;
            #pragma unroll
            for (int nc = 0; nc < 4; ++nc)
                z[mr][t] = fmaf(acc[mr][nc][t], xi[nc * 16], z[mr][t]);
        }
    }

    // reduce over the 16 lanes of each row-group (c = 0..15)
    #pragma unroll
    for (int mask = 1; mask < 16; mask <<= 1) {
        #pragma unroll
        for (int mr = 0; mr < 4; ++mr)
            #pragma unroll
            for (int t = 0; t < 4; ++t)
                z[mr][t] += __shfl_xor(z[mr][t], mask, 64);
    }

    if (c < 4) {  // lane c==t writes rows {Mb + mr*16 + 4g + t}
        const int t = c;
        #pragma unroll
        for (int mr = 0; mr < 4; ++mr) {
            const int row = Mb + mr * 16 + 4 * g + t;
            out[(size_t)row * PAIRS + p] = z[mr][t];
        }
    }
}

// ---- fp32 VALU fallback (correct, ~70us) ----
constexpr int BT     = 64;
constexpr int BTILES = BATCH / BT;

__global__ __launch_bounds__(64) void opn_fp32_kernel(
    const float* __restrict__ x,
    const float* __restrict__ kern,
    float* __restrict__ out)
{
    const int bid   = (int)blockIdx.x;
    const int p     = bid >> 5;
    const int btile = bid & (BTILES - 1);
    const int lane  = (int)threadIdx.x;
    const int b     = btile * BT + lane;

    int i = 0, rem = p;
    while (rem >= FIELDS - 1 - i) { rem -= FIELDS - 1 - i; ++i; }
    const int j = i + 1 + rem;

    const float* xrow_i = x + (size_t)b * (FIELDS * EMBED) + i * EMBED;
    const float* xrow_j = x + (size_t)b * (FIELDS * EMBED) + j * EMBED;
    const float* kp     = kern + (size_t)p * EMBED;

    float acc[EMBED];
    #pragma unroll
    for (int e = 0; e < EMBED; ++e) acc[e] = 0.0f;

    const float4* xj4 = (const float4*)xrow_j;
    #pragma unroll 2
    for (int f4 = 0; f4 < EMBED / 4; ++f4) {
        const float4 v = xj4[f4];
        const float xjf[4] = {v.x, v.y, v.z, v.w};
        #pragma unroll
        for (int s = 0; s < 4; ++s) {
            const float* kf = kp + (size_t)(f4 * 4 + s) * (PAIRS * EMBED);
            #pragma unroll
            for (int e = 0; e < EMBED; ++e)
                acc[e] = fmaf(xjf[s], kf[e], acc[e]);
        }
    }

    float r = 0.0f;
    const float4* xi4 = (const float4*)xrow_i;
    #pragma unroll
    for (int e4 = 0; e4 < EMBED / 4; ++e4) {
        const float4 u = xi4[e4];
        r = fmaf(u.x, acc[e4 * 4 + 0], r);
        r = fmaf(u.y, acc[e4 * 4 + 1], r);
        r = fmaf(u.z, acc[e4 * 4 + 2], r);
        r = fmaf(u.w, acc[e4 * 4 + 3], r);
    }
    out[(size_t)b * PAIRS + p] = r;
}

extern "C" void kernel_launch(void* const* d_in, const int* in_sizes, int n_in,
                              void* d_out, int out_size, void* d_ws, size_t ws_size,
                              hipStream_t stream) {
    const float* x    = (const float*)d_in[0];
    const float* kern = (const float*)d_in[1];
    float*       out  = (float*)d_out;

    if (ws_size < WS_NEED) {
        // Not enough scratch for bf16 staging: pure fp32 path.
        opn_fp32_kernel<<<dim3(PAIRS * BTILES), dim3(64), 0, stream>>>(x, kern, out);
        return;
    }

    char* ws = (char*)d_ws;
    unsigned short* xhi = (unsigned short*)(ws + XH_OFF);
    unsigned short* xlo = (unsigned short*)(ws + XL_OFF);
    unsigned short* kph = (unsigned short*)(ws + KPH_OFF);
    unsigned short* kpl = (unsigned short*)(ws + KPL_OFF);

    convert_x_kernel<<<dim3((unsigned)(XN / 4 / 256)), dim3(256), 0, stream>>>(x, xhi, xlo);
    pack_k_kernel<<<dim3((unsigned)(PAIRS * 2 * 4 * 64 / 256)), dim3(256), 0, stream>>>(kern, kph, kpl);
    opn_mfma_kernel<<<dim3(PAIRS * 8), dim3(256), 0, stream>>>(x, xhi, xlo, kph, kpl, out);
}

// Round 4
// 125.258 us; speedup vs baseline: 1.0096x; 1.0096x over previous
//
#include <hip/hip_runtime.h>
#include <hip/hip_bf16.h>

// out[b,p] = sum_{e,f} x[b,i_p,e] * K[f,p,e] * x[b,j_p,f]
//
// MFMA formulation, per pair p:
//   Y = Xj @ K_p          (2048x64 @ 64x64, bf16 split-3 MFMA, fp32 accum)
//   out[:,p] = rowsum(Y * Xi)   (fp32 VALU epilogue)
//
// Split-bf16: v = hi + lo; acc += Ah*Bh + Ah*Bl + Al*Bh.
//
// R4 changes vs R3 (61us main, VGPR=80, MfmaUtil 15.7% -> latency-bound on
// serialized vmcnt waits):
//  - __launch_bounds__(256, 1): give the RA headroom (~200+ VGPR) so ALL
//    fragment loads are issued before the MFMA block -> one deep pipeline.
//  - x hi/lo conversion inline in the main kernel (VALU, hidden under MFMA);
//    convert_x prepass and its 84MB staging round-trip removed.
//  - single prepass remains: pack_k (B-fragment-packed hi/lo K).

constexpr int BATCH  = 2048;
constexpr int FIELDS = 32;
constexpr int EMBED  = 64;
constexpr int PAIRS  = FIELDS * (FIELDS - 1) / 2;  // 496

typedef __attribute__((ext_vector_type(8))) short  short8;   // 8 bf16 = 4 VGPR
typedef __attribute__((ext_vector_type(4))) float  f32x4;

constexpr size_t KPN     = (size_t)PAIRS * 2 * 4 * 64 * 8;   // 2,031,616 elems
constexpr size_t KPH_OFF = 0;
constexpr size_t KPL_OFF = KPN * 2;
constexpr size_t WS_NEED = KPL_OFF + KPN * 2;                // ~8.1 MB

// ---- fp32 -> bf16 RNE split helpers ----
__device__ __forceinline__ unsigned short f32_to_bf16_rne(float f) {
    unsigned int u = __float_as_uint(f);
    u = u + 0x7fffu + ((u >> 16) & 1u);
    return (unsigned short)(u >> 16);
}
__device__ __forceinline__ float bf16_bits_to_f32(unsigned short h) {
    return __uint_as_float(((unsigned int)h) << 16);
}
__device__ __forceinline__ void split8(const float* v, short8& h8, short8& l8) {
    #pragma unroll
    for (int j = 0; j < 8; ++j) {
        const unsigned short hb = f32_to_bf16_rne(v[j]);
        h8[j] = (short)hb;
        l8[j] = (short)f32_to_bf16_rne(v[j] - bf16_bits_to_f32(hb));
    }
}

// ---- Prepass: kern -> packed B-fragments (hi/lo) ----
// chunk t = ((pair*2 + ks)*4 + nc)*64 + lane, 8 bf16:
//   elem jj = K[f = ks*32 + (lane>>4)*8 + jj][pair][e = nc*16 + (lane&15)]
__global__ __launch_bounds__(256) void pack_k_kernel(
    const float* __restrict__ kern,
    unsigned short* __restrict__ kph,
    unsigned short* __restrict__ kpl)
{
    const int t    = (int)blockIdx.x * 256 + (int)threadIdx.x;  // < PAIRS*512
    const int lane = t & 63;
    const int nc   = (t >> 6) & 3;
    const int ks   = (t >> 8) & 1;
    const int pair = t >> 9;
    const int e    = nc * 16 + (lane & 15);
    const int f0   = ks * 32 + (lane >> 4) * 8;

    float v[8];
    #pragma unroll
    for (int jj = 0; jj < 8; ++jj)
        v[jj] = kern[((size_t)(f0 + jj) * PAIRS + pair) * EMBED + e];

    short8 h8, l8;
    split8(v, h8, l8);
    *(short8*)(kph + (size_t)t * 8) = h8;
    *(short8*)(kpl + (size_t)t * 8) = l8;
}

// ---- Main MFMA kernel ----
// grid = 496 pairs * 8 Mtiles; block = 256 (4 waves); wave tile = 64 batch x 64 e.
__global__ __launch_bounds__(256, 1) void opn_mfma_kernel(
    const float* __restrict__ x,
    const unsigned short* __restrict__ kph,
    const unsigned short* __restrict__ kpl,
    float* __restrict__ out)
{
    const int bid  = (int)blockIdx.x;
    const int p    = bid >> 3;                 // pair (8 consecutive blocks share K_p)
    const int mt   = bid & 7;                  // M tile of 256 batches
    const int wave = (int)threadIdx.x >> 6;
    const int lane = (int)threadIdx.x & 63;
    const int Mb   = mt * 256 + wave * 64;     // this wave's first batch row
    const int g    = lane >> 4;                // k-group / row-group
    const int c    = lane & 15;                // row (A) / col (B,D) within fragment

    // pair -> (i, j) per jnp.triu_indices(FIELDS, k=1)
    int i = 0, rem = p;
    while (rem >= FIELDS - 1 - i) { rem -= FIELDS - 1 - i; ++i; }
    const int jf = i + 1 + rem;

    // ---- Phase 1: issue ALL global loads (x fp32 A-tiles + packed B frags) ----
    float4 xa[4][2][2];  // [mr][ks][half] : 8 consecutive e-floats per (mr,ks)
    #pragma unroll
    for (int mr = 0; mr < 4; ++mr) {
        const int row = Mb + mr * 16 + c;
        const float* base = x + ((size_t)row * FIELDS + jf) * EMBED;
        #pragma unroll
        for (int ks = 0; ks < 2; ++ks) {
            xa[mr][ks][0] = *(const float4*)(base + ks * 32 + g * 8);
            xa[mr][ks][1] = *(const float4*)(base + ks * 32 + g * 8 + 4);
        }
    }
    short8 bh[2][4], bl[2][4];
    #pragma unroll
    for (int ks = 0; ks < 2; ++ks)
        #pragma unroll
        for (int nc = 0; nc < 4; ++nc) {
            const size_t kidx = (((size_t)(p * 2 + ks) * 4 + nc) * 64 + lane) * 8;
            bh[ks][nc] = *(const short8*)(kph + kidx);
            bl[ks][nc] = *(const short8*)(kpl + kidx);
        }

    // ---- Phase 2: convert A to bf16 hi/lo in-register ----
    short8 ah[4][2], al[4][2];
    #pragma unroll
    for (int mr = 0; mr < 4; ++mr)
        #pragma unroll
        for (int ks = 0; ks < 2; ++ks) {
            const float4 a0 = xa[mr][ks][0], a1 = xa[mr][ks][1];
            const float v[8] = {a0.x, a0.y, a0.z, a0.w, a1.x, a1.y, a1.z, a1.w};
            split8(v, ah[mr][ks], al[mr][ks]);
        }

    // ---- Phase 3: 96 MFMAs ----
    f32x4 acc[4][4];
    #pragma unroll
    for (int mr = 0; mr < 4; ++mr)
        #pragma unroll
        for (int nc = 0; nc < 4; ++nc)
            acc[mr][nc] = (f32x4){0.f, 0.f, 0.f, 0.f};

    #pragma unroll
    for (int ks = 0; ks < 2; ++ks)
        #pragma unroll
        for (int mr = 0; mr < 4; ++mr)
            #pragma unroll
            for (int nc = 0; nc < 4; ++nc) {
                acc[mr][nc] = __builtin_amdgcn_mfma_f32_16x16x32_bf16(ah[mr][ks], bh[ks][nc], acc[mr][nc], 0, 0, 0);
                acc[mr][nc] = __builtin_amdgcn_mfma_f32_16x16x32_bf16(ah[mr][ks], bl[ks][nc], acc[mr][nc], 0, 0, 0);
                acc[mr][nc] = __builtin_amdgcn_mfma_f32_16x16x32_bf16(al[mr][ks], bh[ks][nc], acc[mr][nc], 0, 0, 0);
            }

    // ---- Epilogue: out[row, p] = sum_e D[row][e] * x[row][i][e] ----
    // D layout (m89): reg t of acc[mr][nc] = D[row = Mb+mr*16+4g+t][e = nc*16+c]
    float z[4][4];
    #pragma unroll
    for (int mr = 0; mr < 4; ++mr)
        #pragma unroll
        for (int t = 0; t < 4; ++t)
            z[mr][t] = 0.f;

    const size_t xi_base = (size_t)i * EMBED + c;
    #pragma unroll
    for (int mr = 0; mr < 4; ++mr)
        #pragma unroll
        for (int t = 0; t < 4; ++t) {
            const int row = Mb + mr * 16 + 4 * g + t;
            const float* xi = x + (size_t)row * (FIELDS * EMBED) + xi_base;
            #pragma unroll
            for (int nc = 0; nc < 4; ++nc)
                z[mr][t] = fmaf(acc[mr][nc][t], xi[nc * 16], z[mr][t]);
        }

    #pragma unroll
    for (int mask = 1; mask < 16; mask <<= 1)
        #pragma unroll
        for (int mr = 0; mr < 4; ++mr)
            #pragma unroll
            for (int t = 0; t < 4; ++t)
                z[mr][t] += __shfl_xor(z[mr][t], mask, 64);

    if (c < 4) {  // lane c==t writes rows {Mb + mr*16 + 4g + t}
        const int t = c;
        #pragma unroll
        for (int mr = 0; mr < 4; ++mr) {
            const int row = Mb + mr * 16 + 4 * g + t;
            out[(size_t)row * PAIRS + p] = z[mr][t];
        }
    }
}

// ---- fp32 VALU fallback ----
constexpr int BT     = 64;
constexpr int BTILES = BATCH / BT;

__global__ __launch_bounds__(64) void opn_fp32_kernel(
    const float* __restrict__ x,
    const float* __restrict__ kern,
    float* __restrict__ out)
{
    const int bid   = (int)blockIdx.x;
    const int p     = bid >> 5;
    const int btile = bid & (BTILES - 1);
    const int lane  = (int)threadIdx.x;
    const int b     = btile * BT + lane;

    int i = 0, rem = p;
    while (rem >= FIELDS - 1 - i) { rem -= FIELDS - 1 - i; ++i; }
    const int j = i + 1 + rem;

    const float* xrow_i = x + (size_t)b * (FIELDS * EMBED) + i * EMBED;
    const float* xrow_j = x + (size_t)b * (FIELDS * EMBED) + j * EMBED;
    const float* kp     = kern + (size_t)p * EMBED;

    float acc[EMBED];
    #pragma unroll
    for (int e = 0; e < EMBED; ++e) acc[e] = 0.0f;

    const float4* xj4 = (const float4*)xrow_j;
    #pragma unroll 2
    for (int f4 = 0; f4 < EMBED / 4; ++f4) {
        const float4 v = xj4[f4];
        const float xjf[4] = {v.x, v.y, v.z, v.w};
        #pragma unroll
        for (int s = 0; s < 4; ++s) {
            const float* kf = kp + (size_t)(f4 * 4 + s) * (PAIRS * EMBED);
            #pragma unroll
            for (int e = 0; e < EMBED; ++e)
                acc[e] = fmaf(xjf[s], kf[e], acc[e]);
        }
    }

    float r = 0.0f;
    const float4* xi4 = (const float4*)xrow_i;
    #pragma unroll
    for (int e4 = 0; e4 < EMBED / 4; ++e4) {
        const float4 u = xi4[e4];
        r = fmaf(u.x, acc[e4 * 4 + 0], r);
        r = fmaf(u.y, acc[e4 * 4 + 1], r);
        r = fmaf(u.z, acc[e4 * 4 + 2], r);
        r = fmaf(u.w, acc[e4 * 4 + 3], r);
    }
    out[(size_t)b * PAIRS + p] = r;
}

extern "C" void kernel_launch(void* const* d_in, const int* in_sizes, int n_in,
                              void* d_out, int out_size, void* d_ws, size_t ws_size,
                              hipStream_t stream) {
    const float* x    = (const float*)d_in[0];
    const float* kern = (const float*)d_in[1];
    float*       out  = (float*)d_out;

    if (ws_size < WS_NEED) {
        opn_fp32_kernel<<<dim3(PAIRS * BTILES), dim3(64), 0, stream>>>(x, kern, out);
        return;
    }

    char* ws = (char*)d_ws;
    unsigned short* kph = (unsigned short*)(ws + KPH_OFF);
    unsigned short* kpl = (unsigned short*)(ws + KPL_OFF);

    pack_k_kernel<<<dim3(PAIRS * 512 / 256), dim3(256), 0, stream>>>(kern, kph, kpl);
    opn_mfma_kernel<<<dim3(PAIRS * 8), dim3(256), 0, stream>>>(x, kph, kpl, out);
}